// Round 1
// 2160.855 us; speedup vs baseline: 1.1101x; 1.1101x over previous
//
#include <hip/hip_runtime.h>
#include <hip/hip_bf16.h>
#include <stdint.h>
#include <stddef.h>

// Problem constants
#define B_ 32
#define T_ 32
#define S_ 128
#define H_ 512
#define V_ 50257
#define VPAD 50304
#define TH3 1536   // 3*H

typedef __attribute__((ext_vector_type(8))) short short8x;
typedef __attribute__((ext_vector_type(4))) float f32x4;

__device__ __forceinline__ float sigf(float x) { return 1.f / (1.f + __expf(-x)); }
__device__ __forceinline__ float tanhfast(float x) {
  float e = __expf(2.f * x);
  return 1.f - 2.f / (e + 1.f);
}
__device__ __forceinline__ unsigned short f2bf(float x) {
  unsigned int u = __float_as_uint(x);
  return (unsigned short)((u + 0x7fffu + ((u >> 16) & 1u)) >> 16);
}
__device__ __forceinline__ float dot4(float4 a, float4 b) {
  return a.x * b.x + a.y * b.y + a.z * b.z + a.w * b.w;
}

__device__ __forceinline__ void async16(const unsigned short* g, short* l) {
  __builtin_amdgcn_global_load_lds(
      (const __attribute__((address_space(1))) unsigned int*)g,
      (__attribute__((address_space(3))) unsigned int*)l, 16, 0, 0);
}

// ---------------- store-based grid barrier (256 blocks) ----------------
// bar layout: arrive flag for block b at bar[b*32] (128B stride, own line),
//             generation word at bar[8192]. Flags/gen are monotonically
//             increasing phase stamps (ep >= 1); memset(0) before launch.
// No atomic RMWs: arrival is a release-store (fire-and-forget), detection is
// 255 parallel polls by block 0, notify is one release-store of gen.
__device__ __forceinline__ void gridbar(int* bar, int ep) {
  __syncthreads();  // all waves' phase stores drained to L2 (vmcnt(0) in barrier)
  if (blockIdx.x == 0) {
    if (threadIdx.x > 0) {
      const int* f = bar + threadIdx.x * 32;
      while (__hip_atomic_load(f, __ATOMIC_RELAXED, __HIP_MEMORY_SCOPE_AGENT) < ep)
        __builtin_amdgcn_s_sleep(1);
    }
    __syncthreads();
    if (threadIdx.x == 0) {
      __hip_atomic_store(bar + 8192, ep, __ATOMIC_RELEASE, __HIP_MEMORY_SCOPE_AGENT);
      __builtin_amdgcn_fence(__ATOMIC_ACQUIRE, "agent");
    }
    __syncthreads();
  } else {
    if (threadIdx.x == 0) {
      __hip_atomic_store(bar + (int)blockIdx.x * 32, ep, __ATOMIC_RELEASE,
                         __HIP_MEMORY_SCOPE_AGENT);
      const int* g = bar + 8192;
      while (__hip_atomic_load(g, __ATOMIC_RELAXED, __HIP_MEMORY_SCOPE_AGENT) < ep)
        __builtin_amdgcn_s_sleep(1);
      __builtin_amdgcn_fence(__ATOMIC_ACQUIRE, "agent");
    }
    __syncthreads();
  }
}

// ---------------- Ws fp32 -> bf16 (padded to VPAD, pad rows zero) ----------------
__global__ __launch_bounds__(256) void cvt_kernel(const float* __restrict__ Ws,
                                                  unsigned short* __restrict__ outb) {
  size_t i = ((size_t)blockIdx.x * 256 + threadIdx.x) * 4;
  if (i >= (size_t)VPAD * 512) return;
  float4 f;
  if (i < (size_t)V_ * 512) f = *(const float4*)(Ws + i);
  else f = make_float4(0.f, 0.f, 0.f, 0.f);
  ushort4 u;
  u.x = f2bf(f.x); u.y = f2bf(f.y); u.z = f2bf(f.z); u.w = f2bf(f.w);
  *(ushort4*)(outb + i) = u;
}

// ---------------- generic fp32 tiled GEMM: C[M,N] = A[M,512] * Bw[N,512]^T + bias ----
template <int MODE>
__global__ __launch_bounds__(256) void gemm_f32(const float* __restrict__ Asrc,
                                                const float* __restrict__ Bw,
                                                const float* __restrict__ bias,
                                                float* __restrict__ Cout,
                                                const int* __restrict__ tgt, int N) {
  __shared__ __align__(16) float As[16][68];
  __shared__ __align__(16) float Bs[16][68];
  const int tid = threadIdx.x;
  const int tx = tid & 15, ty = tid >> 4;
  const int m0 = blockIdx.y * 64, n0 = blockIdx.x * 64;
  const int srow = tid >> 2, skq = (tid & 3) * 4;
  const float* arow;
  {
    int m = m0 + srow;
    if (MODE == 0) {
      int t = m >> 5, b = m & 31;
      int tok = (t == 0) ? 1 : tgt[b * 32 + t - 1];
      arow = Asrc + (size_t)tok * 512;
    } else {
      int b = m >> 7, s = m & 127;
      arow = Asrc + ((size_t)s * 32 + b) * 512;
    }
  }
  const float* brow = Bw + (size_t)(n0 + srow) * 512;
  float acc[4][4] = {};
  for (int k0 = 0; k0 < 512; k0 += 16) {
    float4 av = *(const float4*)(arow + k0 + skq);
    float4 bv = *(const float4*)(brow + k0 + skq);
    __syncthreads();
    As[skq + 0][srow] = av.x; As[skq + 1][srow] = av.y;
    As[skq + 2][srow] = av.z; As[skq + 3][srow] = av.w;
    Bs[skq + 0][srow] = bv.x; Bs[skq + 1][srow] = bv.y;
    Bs[skq + 2][srow] = bv.z; Bs[skq + 3][srow] = bv.w;
    __syncthreads();
#pragma unroll
    for (int kk = 0; kk < 16; ++kk) {
      float4 a4 = *(const float4*)&As[kk][ty * 4];
      float4 b4 = *(const float4*)&Bs[kk][tx * 4];
      acc[0][0] += a4.x * b4.x; acc[0][1] += a4.x * b4.y; acc[0][2] += a4.x * b4.z; acc[0][3] += a4.x * b4.w;
      acc[1][0] += a4.y * b4.x; acc[1][1] += a4.y * b4.y; acc[1][2] += a4.y * b4.z; acc[1][3] += a4.y * b4.w;
      acc[2][0] += a4.z * b4.x; acc[2][1] += a4.z * b4.y; acc[2][2] += a4.z * b4.z; acc[2][3] += a4.z * b4.w;
      acc[3][0] += a4.w * b4.x; acc[3][1] += a4.w * b4.y; acc[3][2] += a4.w * b4.z; acc[3][3] += a4.w * b4.w;
    }
  }
  float4 b4 = *(const float4*)(bias + n0 + tx * 4);
#pragma unroll
  for (int i = 0; i < 4; ++i) {
    float4 o;
    o.x = acc[i][0] + b4.x; o.y = acc[i][1] + b4.y;
    o.z = acc[i][2] + b4.z; o.w = acc[i][3] + b4.w;
    *(float4*)(Cout + (size_t)(m0 + ty * 4 + i) * N + n0 + tx * 4) = o;
  }
}

// ---------------- persistent pipelined sequential kernel ----------------
// 256 blocks x 256 threads, 1 grid barrier per phase, 36 phases (p = -1..34)
// roles: [0,64)   L0  : gh0(p+1)+cell0 -> x0(p+1)   (gate-triple rows of Whh0)
//        [64,192) L1  : gx1(p)+gh1(p)+cell1 -> x1(p)
//        [192,224)ATT-S: scores/softmax(p-1) -> attn ; CAT rows 0..255   (p-3)
//        [224,256)ATT-C: ctx(p-2)                    ; CAT rows 256..511 (p-3)
// Weight slices are phase-invariant per block -> preloaded ONCE into LDS:
//   L0: 24 rows x 512 of Whh0 (48 KB);  L1: 12+12 rows of Wih1/Whh1 (48 KB);
//   ATT-*: 8 rows x 1024 of Wc (32 KB). All in-loop weight reads hit LDS
//   (broadcast pattern, conflict-free).
__global__ __launch_bounds__(256) void seq_kernel(
    const float* __restrict__ dh, const float* __restrict__ enc,
    const unsigned char* __restrict__ mask,
    const float* __restrict__ Whh, const float* __restrict__ Wih,
    const float* __restrict__ bih, const float* __restrict__ bhh,
    const float* __restrict__ Wc, const float* __restrict__ bc,
    const float* __restrict__ gx0v, const float* __restrict__ encp,
    int* __restrict__ bar, float* __restrict__ x0buf, float* __restrict__ x1buf,
    float* __restrict__ attnbuf, float* __restrict__ ctxbuf,
    unsigned short* __restrict__ cbf, float* __restrict__ out_hf) {
  const int tid = threadIdx.x, bid = blockIdx.x;
  __shared__ __align__(16) float sm[3456];
  __shared__ __align__(16) float wlds[12288];  // 48 KB weight cache
  const int lane = tid & 63, wv = tid >> 6;
  const int bb = lane & 31, rh = lane >> 5;  // lane = (batch, row-half)

  // ---------------- one-time weight preload into LDS ----------------
  if (bid < 64) {
    const int iset0 = bid * 8;
    for (int idx = tid; idx < 24 * 128; idx += 256) {
      const int rloc = idx >> 7, kq = (idx & 127) << 2;
      const int g = rloc >> 3, ii = rloc & 7;
      *(float4*)&wlds[rloc * 512 + kq] =
          *(const float4*)(Whh + (size_t)(g * 512 + iset0 + ii) * 512 + kq);
    }
  } else if (bid < 192) {
    const int iset0 = (bid - 64) * 4;
    for (int idx = tid; idx < 12 * 128; idx += 256) {
      const int rloc = idx >> 7, kq = (idx & 127) << 2;
      const int g = rloc >> 2, ii = rloc & 3;
      const size_t off = (size_t)(1536 + g * 512 + iset0 + ii) * 512 + kq;
      *(float4*)&wlds[rloc * 512 + kq] = *(const float4*)(Wih + off);
      *(float4*)&wlds[(12 + rloc) * 512 + kq] = *(const float4*)(Whh + off);
    }
  } else {
    const int gg0 = (bid < 224) ? (bid - 192) * 8 : 256 + (bid - 224) * 8;
    for (int idx = tid; idx < 8 * 256; idx += 256) {
      const int r = idx >> 8, kq = (idx & 255) << 2;
      *(float4*)&wlds[r * 1024 + kq] =
          *(const float4*)(Wc + (size_t)(gg0 + r) * 1024 + kq);
    }
  }
  __syncthreads();

  for (int p = -1; p <= 34; ++p) {
    if (bid < 64) {
      // ---------------- L0 ----------------
      if (p <= 30) {
        const int iset0 = bid * 8;
        const float* xsrc = (p == -1) ? dh : (x0buf + (p & 1) * 16384);
        float acc[12];
#pragma unroll
        for (int r = 0; r < 12; ++r) acc[r] = 0.f;
        const float* xb = xsrc + bb * 512 + wv * 128;
        for (int c = 0; c < 4; ++c) {
          float4 xv[8];
#pragma unroll
          for (int u = 0; u < 8; ++u) xv[u] = *(const float4*)(xb + c * 32 + u * 4);
#pragma unroll
          for (int rr = 0; rr < 12; ++rr) {
            const int rloc = rh * 12 + rr;
            const float* wrow = wlds + (size_t)rloc * 512 + wv * 128 + c * 32;
#pragma unroll
            for (int u = 0; u < 8; ++u)
              acc[rr] += dot4(*(const float4*)(wrow + u * 4), xv[u]);
          }
        }
        __syncthreads();
#pragma unroll
        for (int rr = 0; rr < 12; ++rr)
          sm[wv * 768 + (rh * 12 + rr) * 32 + bb] = acc[rr];
        __syncthreads();
        {
          const int b2 = tid & 31, i2 = tid >> 5;  // i2 in [0,8)
          const int ig = iset0 + i2;
          float s0 = bhh[ig], s1 = bhh[512 + ig], s2 = bhh[1024 + ig];
#pragma unroll
          for (int w = 0; w < 4; ++w) {
            s0 += sm[w * 768 + (i2) * 32 + b2];
            s1 += sm[w * 768 + (8 + i2) * 32 + b2];
            s2 += sm[w * 768 + (16 + i2) * 32 + b2];
          }
          const float* gx = gx0v + ((size_t)(p + 1) * 32 + b2) * 1536;
          const float hv = xsrc[b2 * 512 + ig];
          const float r = sigf(gx[ig] + s0);
          const float z = sigf(gx[512 + ig] + s1);
          const float n = tanhfast(gx[1024 + ig] + r * s2);
          const float xn = (1.f - z) * n + z * hv;
          x0buf[((p + 1) & 1) * 16384 + b2 * 512 + ig] = xn;
          if (p == 30) out_hf[b2 * 512 + ig] = xn;
        }
      }
    } else if (bid < 192) {
      // ---------------- L1 ----------------
      if (p >= 0 && p <= 31) {
        const int iset0 = (bid - 64) * 4;
        const float* xs0 = x0buf + (p & 1) * 16384;
        const float* xs1 = (p == 0) ? (dh + 16384) : (x1buf + ((p - 1) & 3) * 16384);
        float acc[12];
#pragma unroll
        for (int r = 0; r < 12; ++r) acc[r] = 0.f;
        // pass 1: gx1 = Wih1 . x0(p)
        {
          const float* xb = xs0 + bb * 512 + wv * 128;
          for (int c = 0; c < 4; ++c) {
            float4 xv[8];
#pragma unroll
            for (int u = 0; u < 8; ++u) xv[u] = *(const float4*)(xb + c * 32 + u * 4);
#pragma unroll
            for (int rr = 0; rr < 6; ++rr) {
              const int rloc = rh * 6 + rr;
              const float* wrow = wlds + (size_t)rloc * 512 + wv * 128 + c * 32;
#pragma unroll
              for (int u = 0; u < 8; ++u)
                acc[rr] += dot4(*(const float4*)(wrow + u * 4), xv[u]);
            }
          }
        }
        // pass 2: gh1 = Whh1 . x1(p-1)
        {
          const float* xb = xs1 + bb * 512 + wv * 128;
          for (int c = 0; c < 4; ++c) {
            float4 xv[8];
#pragma unroll
            for (int u = 0; u < 8; ++u) xv[u] = *(const float4*)(xb + c * 32 + u * 4);
#pragma unroll
            for (int rr = 0; rr < 6; ++rr) {
              const int rloc = rh * 6 + rr;
              const float* wrow = wlds + (size_t)(12 + rloc) * 512 + wv * 128 + c * 32;
#pragma unroll
              for (int u = 0; u < 8; ++u)
                acc[6 + rr] += dot4(*(const float4*)(wrow + u * 4), xv[u]);
            }
          }
        }
        __syncthreads();
#pragma unroll
        for (int rr = 0; rr < 6; ++rr) {
          sm[wv * 768 + (rh * 6 + rr) * 32 + bb] = acc[rr];
          sm[wv * 768 + (12 + rh * 6 + rr) * 32 + bb] = acc[6 + rr];
        }
        __syncthreads();
        if (tid < 128) {
          const int b2 = tid & 31, i2 = tid >> 5;  // i2 in [0,4)
          const int ig = iset0 + i2;
          float gxs[3], ghs[3];
#pragma unroll
          for (int g = 0; g < 3; ++g) {
            float a = bih[1536 + g * 512 + ig];
            float h = bhh[1536 + g * 512 + ig];
#pragma unroll
            for (int w = 0; w < 4; ++w) {
              a += sm[w * 768 + (g * 4 + i2) * 32 + b2];
              h += sm[w * 768 + (12 + g * 4 + i2) * 32 + b2];
            }
            gxs[g] = a; ghs[g] = h;
          }
          const float hv = xs1[b2 * 512 + ig];
          const float r = sigf(gxs[0] + ghs[0]);
          const float z = sigf(gxs[1] + ghs[1]);
          const float n = tanhfast(gxs[2] + r * ghs[2]);
          const float xn = (1.f - z) * n + z * hv;
          x1buf[(p & 3) * 16384 + b2 * 512 + ig] = xn;
          if (p == 31) out_hf[16384 + b2 * 512 + ig] = xn;
        }
      }
    } else if (bid < 224) {
      // ---------------- ATT-S : scores + softmax for t = p-1 ----------------
      const int b = bid - 192;
      if (p >= 1 && p <= 32) {
        const int t = p - 1;
        const float* x1 = x1buf + (t & 3) * 16384 + b * 512;
        const int s = tid >> 1, kh = tid & 1;
        const float* ep = encp + ((size_t)b * 128 + s) * 512 + kh * 256;
        const float* xx = x1 + kh * 256;
        float a = 0.f;
#pragma unroll 8
        for (int k = 0; k < 256; k += 4)
          a += dot4(*(const float4*)(ep + k), *(const float4*)(xx + k));
        sm[tid] = a;
        __syncthreads();
        if (tid < 128) {
          float sc = sm[2 * tid] + sm[2 * tid + 1];
          if (mask[b * 128 + tid]) sc = -1e9f;
          sm[256 + tid] = sc;
        }
        __syncthreads();
        if (tid < 64) {
          float m1 = fmaxf(sm[256 + tid], sm[256 + tid + 64]);
#pragma unroll
          for (int off = 32; off; off >>= 1) m1 = fmaxf(m1, __shfl_xor(m1, off));
          float e0 = __expf(sm[256 + tid] - m1), e1 = __expf(sm[256 + tid + 64] - m1);
          float ssum = e0 + e1;
#pragma unroll
          for (int off = 32; off; off >>= 1) ssum += __shfl_xor(ssum, off);
          float inv = 1.f / ssum;
          sm[384 + tid] = e0 * inv;
          sm[384 + tid + 64] = e1 * inv;
        }
        __syncthreads();
        if (tid < 128) attnbuf[(t & 1) * 4096 + b * 128 + tid] = sm[384 + tid];
      }
      // CAT rows 0..255, t = p-3
      if (p >= 3) {
        const int t = p - 3;
        const int gg = (bid - 192) * 8 + (tid >> 5);
        const int b2 = tid & 31;
        const float* ctx = ctxbuf + (t & 1) * 16384 + b2 * 512;
        const float* x1c = x1buf + (t & 3) * 16384 + b2 * 512;
        const float* wr = wlds + (size_t)(tid >> 5) * 1024;
        float a = bc[gg];
#pragma unroll 4
        for (int k = 0; k < 512; k += 4) a += dot4(*(const float4*)(wr + k), *(const float4*)(ctx + k));
#pragma unroll 4
        for (int k = 0; k < 512; k += 4) a += dot4(*(const float4*)(wr + 512 + k), *(const float4*)(x1c + k));
        cbf[((size_t)t * 32 + b2) * 512 + gg] = f2bf(tanhfast(a));
      }
    } else {
      // ---------------- ATT-C : ctx for t = p-2 ----------------
      const int b = bid - 224;
      if (p >= 2 && p <= 33) {
        const int t = p - 2;
        if (tid < 128) sm[tid] = attnbuf[(t & 1) * 4096 + b * 128 + tid];
        __syncthreads();
        if (tid < 128) {
          const int h4 = tid * 4;
          float4 c = make_float4(0.f, 0.f, 0.f, 0.f);
#pragma unroll 8
          for (int s = 0; s < 128; ++s) {
            const float a = sm[s];
            const float4 e = *(const float4*)(enc + ((size_t)s * 32 + b) * 512 + h4);
            c.x += a * e.x; c.y += a * e.y; c.z += a * e.z; c.w += a * e.w;
          }
          *(float4*)(ctxbuf + (t & 1) * 16384 + b * 512 + h4) = c;
        }
        __syncthreads();
      }
      // CAT rows 256..511, t = p-3
      if (p >= 3) {
        const int t = p - 3;
        const int gg = 256 + (bid - 224) * 8 + (tid >> 5);
        const int b2 = tid & 31;
        const float* ctx = ctxbuf + (t & 1) * 16384 + b2 * 512;
        const float* x1c = x1buf + (t & 3) * 16384 + b2 * 512;
        const float* wr = wlds + (size_t)(tid >> 5) * 1024;
        float a = bc[gg];
#pragma unroll 4
        for (int k = 0; k < 512; k += 4) a += dot4(*(const float4*)(wr + k), *(const float4*)(ctx + k));
#pragma unroll 4
        for (int k = 0; k < 512; k += 4) a += dot4(*(const float4*)(wr + 512 + k), *(const float4*)(x1c + k));
        cbf[((size_t)t * 32 + b2) * 512 + gg] = f2bf(tanhfast(a));
      }
    }
    if (p < 34) gridbar(bar, p + 2);
  }
}

// ---------------- bf16 MFMA vocab projection: C[1024,V] = concat * Ws^T + bs ---------
__global__ __launch_bounds__(256) void proj_kernel(const unsigned short* __restrict__ A,
                                                   const unsigned short* __restrict__ Bw,
                                                   const float* __restrict__ bs,
                                                   float* __restrict__ C) {
  __shared__ short8x AsV[512];
  __shared__ short8x BsV[512];
  short* As = (short*)AsV;
  short* Bs = (short*)BsV;
  const int tid = threadIdx.x;
  const int lane = tid & 63, wv = tid >> 6;
  const int m0 = blockIdx.x * 128;
  const int n0 = blockIdx.y * 128;
  const int wm = (wv >> 1) * 64, wn = (wv & 1) * 64;
  f32x4 acc[4][4] = {};
  const int sr = lane >> 2, sb = (lane & 3) * 8;
  const unsigned short* gA1 = A + (size_t)(m0 + wv * 16 + sr) * 512 + sb;
  const unsigned short* gA2 = gA1 + (size_t)64 * 512;
  const unsigned short* gB1 = Bw + (size_t)(n0 + wv * 16 + sr) * 512 + sb;
  const unsigned short* gB2 = gB1 + (size_t)64 * 512;
  short* lA1 = As + (wv * 16) * 32;
  short* lA2 = As + (64 + wv * 16) * 32;
  short* lB1 = Bs + (wv * 16) * 32;
  short* lB2 = Bs + (64 + wv * 16) * 32;
  const int rA = wm + (lane & 15);
  const int rB = wn + (lane & 15);
  const int kb = (lane >> 4) * 8;
  for (int kt = 0; kt < 16; ++kt) {
    const int ko = kt * 32;
    __syncthreads();
    async16(gA1 + ko, lA1);
    async16(gA2 + ko, lA2);
    async16(gB1 + ko, lB1);
    async16(gB2 + ko, lB2);
    __syncthreads();
    short8x af[4], bf[4];
#pragma unroll
    for (int i = 0; i < 4; ++i) af[i] = *(const short8x*)(As + (rA + i * 16) * 32 + kb);
#pragma unroll
    for (int i = 0; i < 4; ++i) bf[i] = *(const short8x*)(Bs + (rB + i * 16) * 32 + kb);
#pragma unroll
    for (int mo = 0; mo < 4; ++mo)
#pragma unroll
      for (int no = 0; no < 4; ++no)
        acc[mo][no] = __builtin_amdgcn_mfma_f32_16x16x32_bf16(af[mo], bf[no], acc[mo][no], 0, 0, 0);
  }
#pragma unroll
  for (int no = 0; no < 4; ++no) {
    const int col = n0 + wn + no * 16 + (lane & 15);
    if (col < V_) {
      const float bsv = bs[col];
#pragma unroll
      for (int mo = 0; mo < 4; ++mo) {
        const int row = m0 + wm + mo * 16 + ((lane >> 4) << 2);
        f32x4 v = acc[mo][no];
        C[(size_t)(row + 0) * V_ + col] = v[0] + bsv;
        C[(size_t)(row + 1) * V_ + col] = v[1] + bsv;
        C[(size_t)(row + 2) * V_ + col] = v[2] + bsv;
        C[(size_t)(row + 3) * V_ + col] = v[3] + bsv;
      }
    }
  }
}

extern "C" void kernel_launch(void* const* d_in, const int* in_sizes, int n_in,
                              void* d_out, int out_size, void* d_ws, size_t ws_size,
                              hipStream_t stream) {
  (void)in_sizes; (void)n_in; (void)out_size; (void)ws_size;
  const int* tgt = (const int*)d_in[0];
  const float* dh = (const float*)d_in[1];
  const float* enc = (const float*)d_in[2];
  const unsigned char* mask = (const unsigned char*)d_in[3];
  const float* embW = (const float*)d_in[4];
  const float* Wih = (const float*)d_in[5];
  const float* Whh = (const float*)d_in[6];
  const float* bih = (const float*)d_in[7];
  const float* bhh = (const float*)d_in[8];
  const float* Wa = (const float*)d_in[9];
  const float* ba = (const float*)d_in[10];
  const float* Wc = (const float*)d_in[11];
  const float* bc = (const float*)d_in[12];
  const float* Ws = (const float*)d_in[13];
  const float* bs = (const float*)d_in[14];
  float* out = (float*)d_out;

  // workspace layout (~67.8 MB)
  char* w = (char*)d_ws;
  int* bar = (int*)w;                                   // 40960 B: flags @ b*32, gen @ 8192
  float* x0buf = (float*)(w + 40960);                   // 2*16384 f
  float* x1buf = x0buf + 32768;                         // 4*16384 f
  float* attnbuf = x1buf + 65536;                       // 2*32*128 f
  float* ctxbuf = attnbuf + 8192;                       // 2*16384 f
  float* gx0v = ctxbuf + 32768;                         // 1024*1536 f
  float* encp = gx0v + 1572864;                         // 4096*512 f
  unsigned short* cbf = (unsigned short*)(encp + 2097152);  // 1024*512 bf16
  unsigned short* wsb = cbf + 524288;                   // VPAD*512 bf16

  hipMemsetAsync(bar, 0, 40960, stream);
  cvt_kernel<<<25152, 256, 0, stream>>>(Ws, wsb);
  gemm_f32<0><<<dim3(24, 16), 256, 0, stream>>>(embW, Wih, bih, gx0v, tgt, 1536);
  gemm_f32<1><<<dim3(8, 64), 256, 0, stream>>>(enc, Wa, ba, encp, nullptr, 512);
  seq_kernel<<<256, 256, 0, stream>>>(dh, enc, mask, Whh, Wih, bih, bhh, Wc, bc,
                                      gx0v, encp, bar, x0buf, x1buf, attnbuf, ctxbuf,
                                      cbf, out + (size_t)1024 * V_);
  proj_kernel<<<dim3(8, 393), 256, 0, stream>>>(cbf, wsb, bs, out);
}

// Round 2
// 1932.732 us; speedup vs baseline: 1.2411x; 1.1180x over previous
//
#include <hip/hip_runtime.h>
#include <hip/hip_bf16.h>
#include <stdint.h>
#include <stddef.h>

// Problem constants
#define B_ 32
#define T_ 32
#define S_ 128
#define H_ 512
#define V_ 50257
#define VPAD 50304
#define TH3 1536   // 3*H

typedef __attribute__((ext_vector_type(8))) short short8x;
typedef __attribute__((ext_vector_type(4))) float f32x4;

__device__ __forceinline__ float sigf(float x) { return 1.f / (1.f + __expf(-x)); }
__device__ __forceinline__ float tanhfast(float x) {
  float e = __expf(2.f * x);
  return 1.f - 2.f / (e + 1.f);
}
__device__ __forceinline__ unsigned short f2bf(float x) {
  unsigned int u = __float_as_uint(x);
  return (unsigned short)((u + 0x7fffu + ((u >> 16) & 1u)) >> 16);
}
__device__ __forceinline__ float dot4(float4 a, float4 b) {
  return a.x * b.x + a.y * b.y + a.z * b.z + a.w * b.w;
}

__device__ __forceinline__ void async16(const unsigned short* g, short* l) {
  __builtin_amdgcn_global_load_lds(
      (const __attribute__((address_space(1))) unsigned int*)g,
      (__attribute__((address_space(3))) unsigned int*)l, 16, 0, 0);
}

// Write-through (L1+L2 bypass) stores: data reaches the coherent point (L3)
// so other XCDs' cached first-touch reads of write-once slots see it.
__device__ __forceinline__ void store_wt(float* p, float v) {
  asm volatile("global_store_dword %0, %1, off sc0 sc1" :: "v"(p), "v"(v) : "memory");
}
__device__ __forceinline__ void store_wt4(float* p, f32x4 v) {
  asm volatile("global_store_dwordx4 %0, %1, off sc0 sc1" :: "v"(p), "v"(v) : "memory");
}

// ---------------- fence-free single-hop grid barrier (256 blocks) ----------------
// Flag for block b lives at bar[b*32] (128B stride). All flag traffic is
// system-scope (sc0 sc1 = bypass L1+L2) so polls read the coherent point
// directly instead of waiting for stale-L2 eviction. Data ordering: explicit
// s_waitcnt vmcnt(0) drains each thread's write-through stores (inline-asm
// stores are invisible to the compiler's waitcnt bookkeeping) before the
// arrive-store. Single visibility hop: wave 0 of EVERY block polls all 256
// flags (4 per thread). No acquire/release fences anywhere.
__device__ __forceinline__ void gridbar(int* bar, int ep) {
  asm volatile("s_waitcnt vmcnt(0)" ::: "memory");
  __syncthreads();
  const int tid = threadIdx.x;
  if (tid == 0)
    __hip_atomic_store(bar + (int)blockIdx.x * 32, ep, __ATOMIC_RELAXED,
                       __HIP_MEMORY_SCOPE_SYSTEM);
  if (tid < 64) {
    int got = 0;
    while (got != 15) {
#pragma unroll
      for (int j = 0; j < 4; ++j)
        if (!((got >> j) & 1)) {
          int v = __hip_atomic_load(bar + (tid * 4 + j) * 32, __ATOMIC_RELAXED,
                                    __HIP_MEMORY_SCOPE_SYSTEM);
          if (v >= ep) got |= (1 << j);
        }
      if (got != 15) __builtin_amdgcn_s_sleep(2);
    }
  }
  __syncthreads();
}

// ---------------- Ws fp32 -> bf16 (padded to VPAD, pad rows zero) ----------------
__global__ __launch_bounds__(256) void cvt_kernel(const float* __restrict__ Ws,
                                                  unsigned short* __restrict__ outb) {
  size_t i = ((size_t)blockIdx.x * 256 + threadIdx.x) * 4;
  if (i >= (size_t)VPAD * 512) return;
  float4 f;
  if (i < (size_t)V_ * 512) f = *(const float4*)(Ws + i);
  else f = make_float4(0.f, 0.f, 0.f, 0.f);
  ushort4 u;
  u.x = f2bf(f.x); u.y = f2bf(f.y); u.z = f2bf(f.z); u.w = f2bf(f.w);
  *(ushort4*)(outb + i) = u;
}

// ---------------- generic fp32 tiled GEMM: C[M,N] = A[M,512] * Bw[N,512]^T + bias ----
template <int MODE>
__global__ __launch_bounds__(256) void gemm_f32(const float* __restrict__ Asrc,
                                                const float* __restrict__ Bw,
                                                const float* __restrict__ bias,
                                                float* __restrict__ Cout,
                                                const int* __restrict__ tgt, int N) {
  __shared__ __align__(16) float As[16][68];
  __shared__ __align__(16) float Bs[16][68];
  const int tid = threadIdx.x;
  const int tx = tid & 15, ty = tid >> 4;
  const int m0 = blockIdx.y * 64, n0 = blockIdx.x * 64;
  const int srow = tid >> 2, skq = (tid & 3) * 4;
  const float* arow;
  {
    int m = m0 + srow;
    if (MODE == 0) {
      int t = m >> 5, b = m & 31;
      int tok = (t == 0) ? 1 : tgt[b * 32 + t - 1];
      arow = Asrc + (size_t)tok * 512;
    } else {
      int b = m >> 7, s = m & 127;
      arow = Asrc + ((size_t)s * 32 + b) * 512;
    }
  }
  const float* brow = Bw + (size_t)(n0 + srow) * 512;
  float acc[4][4] = {};
  for (int k0 = 0; k0 < 512; k0 += 16) {
    float4 av = *(const float4*)(arow + k0 + skq);
    float4 bv = *(const float4*)(brow + k0 + skq);
    __syncthreads();
    As[skq + 0][srow] = av.x; As[skq + 1][srow] = av.y;
    As[skq + 2][srow] = av.z; As[skq + 3][srow] = av.w;
    Bs[skq + 0][srow] = bv.x; Bs[skq + 1][srow] = bv.y;
    Bs[skq + 2][srow] = bv.z; Bs[skq + 3][srow] = bv.w;
    __syncthreads();
#pragma unroll
    for (int kk = 0; kk < 16; ++kk) {
      float4 a4 = *(const float4*)&As[kk][ty * 4];
      float4 b4 = *(const float4*)&Bs[kk][tx * 4];
      acc[0][0] += a4.x * b4.x; acc[0][1] += a4.x * b4.y; acc[0][2] += a4.x * b4.z; acc[0][3] += a4.x * b4.w;
      acc[1][0] += a4.y * b4.x; acc[1][1] += a4.y * b4.y; acc[1][2] += a4.y * b4.z; acc[1][3] += a4.y * b4.w;
      acc[2][0] += a4.z * b4.x; acc[2][1] += a4.z * b4.y; acc[2][2] += a4.z * b4.z; acc[2][3] += a4.z * b4.w;
      acc[3][0] += a4.w * b4.x; acc[3][1] += a4.w * b4.y; acc[3][2] += a4.w * b4.z; acc[3][3] += a4.w * b4.w;
    }
  }
  float4 b4 = *(const float4*)(bias + n0 + tx * 4);
#pragma unroll
  for (int i = 0; i < 4; ++i) {
    float4 o;
    o.x = acc[i][0] + b4.x; o.y = acc[i][1] + b4.y;
    o.z = acc[i][2] + b4.z; o.w = acc[i][3] + b4.w;
    *(float4*)(Cout + (size_t)(m0 + ty * 4 + i) * N + n0 + tx * 4) = o;
  }
}

// ---------------- persistent pipelined sequential kernel ----------------
// 256 blocks x 256 threads, 1 grid barrier per phase, 36 phases (p = -1..34)
// roles: [0,64)   L0  : gh0(p+1)+cell0 -> x0(p+1)
//        [64,192) L1  : gx1(p)+gh1(p)+cell1 -> x1(p)
//        [192,224)ATT-S: scores/softmax(p-1) -> attn ; CAT rows 0..255   (p-3)
//        [224,256)ATT-C: ctx(p-2)                    ; CAT rows 256..511 (p-3)
// Weights preloaded once into LDS. Cross-block buffers (x0/x1/attn/ctx) are
// WRITE-ONCE SLOTTED (one 64KB/16KB slot per timestep): producers store
// write-through (sc0 sc1), consumers use normal cached loads (first touch is
// guaranteed post-write, so L1/L2 can never hold a stale copy and the x8
// broadcast redundancy is absorbed by the caches).
__global__ __launch_bounds__(256) void seq_kernel(
    const float* __restrict__ dh, const float* __restrict__ enc,
    const unsigned char* __restrict__ mask,
    const float* __restrict__ Whh, const float* __restrict__ Wih,
    const float* __restrict__ bih, const float* __restrict__ bhh,
    const float* __restrict__ Wc, const float* __restrict__ bc,
    const float* __restrict__ gx0v, const float* __restrict__ encp,
    int* __restrict__ bar, float* __restrict__ x0buf, float* __restrict__ x1buf,
    float* __restrict__ attnbuf, float* __restrict__ ctxbuf,
    unsigned short* __restrict__ cbf, float* __restrict__ out_hf) {
  const int tid = threadIdx.x, bid = blockIdx.x;
  __shared__ __align__(16) float sm[3456];
  __shared__ __align__(16) float wlds[12288];  // 48 KB weight cache
  const int lane = tid & 63, wv = tid >> 6;
  const int bb = lane & 31, rh = lane >> 5;  // lane = (batch, row-half)

  // ---------------- one-time weight preload into LDS ----------------
  if (bid < 64) {
    const int iset0 = bid * 8;
    for (int idx = tid; idx < 24 * 128; idx += 256) {
      const int rloc = idx >> 7, kq = (idx & 127) << 2;
      const int g = rloc >> 3, ii = rloc & 7;
      *(float4*)&wlds[rloc * 512 + kq] =
          *(const float4*)(Whh + (size_t)(g * 512 + iset0 + ii) * 512 + kq);
    }
  } else if (bid < 192) {
    const int iset0 = (bid - 64) * 4;
    for (int idx = tid; idx < 12 * 128; idx += 256) {
      const int rloc = idx >> 7, kq = (idx & 127) << 2;
      const int g = rloc >> 2, ii = rloc & 3;
      const size_t off = (size_t)(1536 + g * 512 + iset0 + ii) * 512 + kq;
      *(float4*)&wlds[rloc * 512 + kq] = *(const float4*)(Wih + off);
      *(float4*)&wlds[(12 + rloc) * 512 + kq] = *(const float4*)(Whh + off);
    }
  } else {
    const int gg0 = (bid < 224) ? (bid - 192) * 8 : 256 + (bid - 224) * 8;
    for (int idx = tid; idx < 8 * 256; idx += 256) {
      const int r = idx >> 8, kq = (idx & 255) << 2;
      *(float4*)&wlds[r * 1024 + kq] =
          *(const float4*)(Wc + (size_t)(gg0 + r) * 1024 + kq);
    }
  }
  __syncthreads();

  for (int p = -1; p <= 34; ++p) {
    if (bid < 64) {
      // ---------------- L0 ----------------
      if (p <= 30) {
        const int iset0 = bid * 8;
        const float* xsrc = (p == -1) ? dh : (x0buf + (size_t)p * 16384);
        float acc[12];
#pragma unroll
        for (int r = 0; r < 12; ++r) acc[r] = 0.f;
        const float* xb = xsrc + bb * 512 + wv * 128;
        for (int c = 0; c < 4; ++c) {
          float4 xv[8];
#pragma unroll
          for (int u = 0; u < 8; ++u) xv[u] = *(const float4*)(xb + c * 32 + u * 4);
#pragma unroll
          for (int rr = 0; rr < 12; ++rr) {
            const int rloc = rh * 12 + rr;
            const float* wrow = wlds + (size_t)rloc * 512 + wv * 128 + c * 32;
#pragma unroll
            for (int u = 0; u < 8; ++u)
              acc[rr] += dot4(*(const float4*)(wrow + u * 4), xv[u]);
          }
        }
        __syncthreads();
#pragma unroll
        for (int rr = 0; rr < 12; ++rr)
          sm[wv * 768 + (rh * 12 + rr) * 32 + bb] = acc[rr];
        __syncthreads();
        {
          const int b2 = tid & 31, i2 = tid >> 5;  // i2 in [0,8)
          const int ig = iset0 + i2;
          float s0 = bhh[ig], s1 = bhh[512 + ig], s2 = bhh[1024 + ig];
#pragma unroll
          for (int w = 0; w < 4; ++w) {
            s0 += sm[w * 768 + (i2) * 32 + b2];
            s1 += sm[w * 768 + (8 + i2) * 32 + b2];
            s2 += sm[w * 768 + (16 + i2) * 32 + b2];
          }
          const float* gx = gx0v + ((size_t)(p + 1) * 32 + b2) * 1536;
          const float hv = xsrc[b2 * 512 + ig];
          const float r = sigf(gx[ig] + s0);
          const float z = sigf(gx[512 + ig] + s1);
          const float n = tanhfast(gx[1024 + ig] + r * s2);
          const float xn = (1.f - z) * n + z * hv;
          store_wt(x0buf + (size_t)(p + 1) * 16384 + b2 * 512 + ig, xn);
          if (p == 30) out_hf[b2 * 512 + ig] = xn;
        }
      }
    } else if (bid < 192) {
      // ---------------- L1 ----------------
      if (p >= 0 && p <= 31) {
        const int iset0 = (bid - 64) * 4;
        const float* xs0 = x0buf + (size_t)p * 16384;
        const float* xs1 = (p == 0) ? (dh + 16384) : (x1buf + (size_t)(p - 1) * 16384);
        float acc[12];
#pragma unroll
        for (int r = 0; r < 12; ++r) acc[r] = 0.f;
        // pass 1: gx1 = Wih1 . x0(p)
        {
          const float* xb = xs0 + bb * 512 + wv * 128;
          for (int c = 0; c < 4; ++c) {
            float4 xv[8];
#pragma unroll
            for (int u = 0; u < 8; ++u) xv[u] = *(const float4*)(xb + c * 32 + u * 4);
#pragma unroll
            for (int rr = 0; rr < 6; ++rr) {
              const int rloc = rh * 6 + rr;
              const float* wrow = wlds + (size_t)rloc * 512 + wv * 128 + c * 32;
#pragma unroll
              for (int u = 0; u < 8; ++u)
                acc[rr] += dot4(*(const float4*)(wrow + u * 4), xv[u]);
            }
          }
        }
        // pass 2: gh1 = Whh1 . x1(p-1)
        {
          const float* xb = xs1 + bb * 512 + wv * 128;
          for (int c = 0; c < 4; ++c) {
            float4 xv[8];
#pragma unroll
            for (int u = 0; u < 8; ++u) xv[u] = *(const float4*)(xb + c * 32 + u * 4);
#pragma unroll
            for (int rr = 0; rr < 6; ++rr) {
              const int rloc = rh * 6 + rr;
              const float* wrow = wlds + (size_t)(12 + rloc) * 512 + wv * 128 + c * 32;
#pragma unroll
              for (int u = 0; u < 8; ++u)
                acc[6 + rr] += dot4(*(const float4*)(wrow + u * 4), xv[u]);
            }
          }
        }
        __syncthreads();
#pragma unroll
        for (int rr = 0; rr < 6; ++rr) {
          sm[wv * 768 + (rh * 6 + rr) * 32 + bb] = acc[rr];
          sm[wv * 768 + (12 + rh * 6 + rr) * 32 + bb] = acc[6 + rr];
        }
        __syncthreads();
        if (tid < 128) {
          const int b2 = tid & 31, i2 = tid >> 5;  // i2 in [0,4)
          const int ig = iset0 + i2;
          float gxs[3], ghs[3];
#pragma unroll
          for (int g = 0; g < 3; ++g) {
            float a = bih[1536 + g * 512 + ig];
            float h = bhh[1536 + g * 512 + ig];
#pragma unroll
            for (int w = 0; w < 4; ++w) {
              a += sm[w * 768 + (g * 4 + i2) * 32 + b2];
              h += sm[w * 768 + (12 + g * 4 + i2) * 32 + b2];
            }
            gxs[g] = a; ghs[g] = h;
          }
          const float hv = xs1[b2 * 512 + ig];
          const float r = sigf(gxs[0] + ghs[0]);
          const float z = sigf(gxs[1] + ghs[1]);
          const float n = tanhfast(gxs[2] + r * ghs[2]);
          const float xn = (1.f - z) * n + z * hv;
          store_wt(x1buf + (size_t)p * 16384 + b2 * 512 + ig, xn);
          if (p == 31) out_hf[16384 + b2 * 512 + ig] = xn;
        }
      }
    } else if (bid < 224) {
      // ---------------- ATT-S : scores + softmax for t = p-1 ----------------
      const int b = bid - 192;
      if (p >= 1 && p <= 32) {
        const int t = p - 1;
        const float* x1 = x1buf + (size_t)t * 16384 + b * 512;
        const int s = tid >> 1, kh = tid & 1;
        const float* ep = encp + ((size_t)b * 128 + s) * 512 + kh * 256;
        const float* xx = x1 + kh * 256;
        float a = 0.f;
#pragma unroll 8
        for (int k = 0; k < 256; k += 4)
          a += dot4(*(const float4*)(ep + k), *(const float4*)(xx + k));
        sm[tid] = a;
        __syncthreads();
        if (tid < 128) {
          float sc = sm[2 * tid] + sm[2 * tid + 1];
          if (mask[b * 128 + tid]) sc = -1e9f;
          sm[256 + tid] = sc;
        }
        __syncthreads();
        if (tid < 64) {
          float m1 = fmaxf(sm[256 + tid], sm[256 + tid + 64]);
#pragma unroll
          for (int off = 32; off; off >>= 1) m1 = fmaxf(m1, __shfl_xor(m1, off));
          float e0 = __expf(sm[256 + tid] - m1), e1 = __expf(sm[256 + tid + 64] - m1);
          float ssum = e0 + e1;
#pragma unroll
          for (int off = 32; off; off >>= 1) ssum += __shfl_xor(ssum, off);
          float inv = 1.f / ssum;
          sm[384 + tid] = e0 * inv;
          sm[384 + tid + 64] = e1 * inv;
        }
        __syncthreads();
        if (tid < 128) store_wt(attnbuf + (size_t)t * 4096 + b * 128 + tid, sm[384 + tid]);
      }
      // CAT rows 0..255, t = p-3
      if (p >= 3) {
        const int t = p - 3;
        const int gg = (bid - 192) * 8 + (tid >> 5);
        const int b2 = tid & 31;
        const float* ctx = ctxbuf + (size_t)t * 16384 + b2 * 512;
        const float* x1c = x1buf + (size_t)t * 16384 + b2 * 512;
        const float* wr = wlds + (size_t)(tid >> 5) * 1024;
        float a = bc[gg];
#pragma unroll 4
        for (int k = 0; k < 512; k += 4) a += dot4(*(const float4*)(wr + k), *(const float4*)(ctx + k));
#pragma unroll 4
        for (int k = 0; k < 512; k += 4) a += dot4(*(const float4*)(wr + 512 + k), *(const float4*)(x1c + k));
        cbf[((size_t)t * 32 + b2) * 512 + gg] = f2bf(tanhfast(a));
      }
    } else {
      // ---------------- ATT-C : ctx for t = p-2 ----------------
      const int b = bid - 224;
      if (p >= 2 && p <= 33) {
        const int t = p - 2;
        if (tid < 128) sm[tid] = attnbuf[(size_t)t * 4096 + b * 128 + tid];
        __syncthreads();
        if (tid < 128) {
          const int h4 = tid * 4;
          float4 c = make_float4(0.f, 0.f, 0.f, 0.f);
#pragma unroll 8
          for (int s = 0; s < 128; ++s) {
            const float a = sm[s];
            const float4 e = *(const float4*)(enc + ((size_t)s * 32 + b) * 512 + h4);
            c.x += a * e.x; c.y += a * e.y; c.z += a * e.z; c.w += a * e.w;
          }
          f32x4 cc = {c.x, c.y, c.z, c.w};
          store_wt4(ctxbuf + (size_t)t * 16384 + b * 512 + h4, cc);
        }
        __syncthreads();
      }
      // CAT rows 256..511, t = p-3
      if (p >= 3) {
        const int t = p - 3;
        const int gg = 256 + (bid - 224) * 8 + (tid >> 5);
        const int b2 = tid & 31;
        const float* ctx = ctxbuf + (size_t)t * 16384 + b2 * 512;
        const float* x1c = x1buf + (size_t)t * 16384 + b2 * 512;
        const float* wr = wlds + (size_t)(tid >> 5) * 1024;
        float a = bc[gg];
#pragma unroll 4
        for (int k = 0; k < 512; k += 4) a += dot4(*(const float4*)(wr + k), *(const float4*)(ctx + k));
#pragma unroll 4
        for (int k = 0; k < 512; k += 4) a += dot4(*(const float4*)(wr + 512 + k), *(const float4*)(x1c + k));
        cbf[((size_t)t * 32 + b2) * 512 + gg] = f2bf(tanhfast(a));
      }
    }
    if (p < 34) gridbar(bar, p + 2);
  }
}

// ---------------- bf16 MFMA vocab projection: C[1024,V] = concat * Ws^T + bs ---------
__global__ __launch_bounds__(256) void proj_kernel(const unsigned short* __restrict__ A,
                                                   const unsigned short* __restrict__ Bw,
                                                   const float* __restrict__ bs,
                                                   float* __restrict__ C) {
  __shared__ short8x AsV[512];
  __shared__ short8x BsV[512];
  short* As = (short*)AsV;
  short* Bs = (short*)BsV;
  const int tid = threadIdx.x;
  const int lane = tid & 63, wv = tid >> 6;
  const int m0 = blockIdx.x * 128;
  const int n0 = blockIdx.y * 128;
  const int wm = (wv >> 1) * 64, wn = (wv & 1) * 64;
  f32x4 acc[4][4] = {};
  const int sr = lane >> 2, sb = (lane & 3) * 8;
  const unsigned short* gA1 = A + (size_t)(m0 + wv * 16 + sr) * 512 + sb;
  const unsigned short* gA2 = gA1 + (size_t)64 * 512;
  const unsigned short* gB1 = Bw + (size_t)(n0 + wv * 16 + sr) * 512 + sb;
  const unsigned short* gB2 = gB1 + (size_t)64 * 512;
  short* lA1 = As + (wv * 16) * 32;
  short* lA2 = As + (64 + wv * 16) * 32;
  short* lB1 = Bs + (wv * 16) * 32;
  short* lB2 = Bs + (64 + wv * 16) * 32;
  const int rA = wm + (lane & 15);
  const int rB = wn + (lane & 15);
  const int kb = (lane >> 4) * 8;
  for (int kt = 0; kt < 16; ++kt) {
    const int ko = kt * 32;
    __syncthreads();
    async16(gA1 + ko, lA1);
    async16(gA2 + ko, lA2);
    async16(gB1 + ko, lB1);
    async16(gB2 + ko, lB2);
    __syncthreads();
    short8x af[4], bf[4];
#pragma unroll
    for (int i = 0; i < 4; ++i) af[i] = *(const short8x*)(As + (rA + i * 16) * 32 + kb);
#pragma unroll
    for (int i = 0; i < 4; ++i) bf[i] = *(const short8x*)(Bs + (rB + i * 16) * 32 + kb);
#pragma unroll
    for (int mo = 0; mo < 4; ++mo)
#pragma unroll
      for (int no = 0; no < 4; ++no)
        acc[mo][no] = __builtin_amdgcn_mfma_f32_16x16x32_bf16(af[mo], bf[no], acc[mo][no], 0, 0, 0);
  }
#pragma unroll
  for (int no = 0; no < 4; ++no) {
    const int col = n0 + wn + no * 16 + (lane & 15);
    if (col < V_) {
      const float bsv = bs[col];
#pragma unroll
      for (int mo = 0; mo < 4; ++mo) {
        const int row = m0 + wm + mo * 16 + ((lane >> 4) << 2);
        f32x4 v = acc[mo][no];
        C[(size_t)(row + 0) * V_ + col] = v[0] + bsv;
        C[(size_t)(row + 1) * V_ + col] = v[1] + bsv;
        C[(size_t)(row + 2) * V_ + col] = v[2] + bsv;
        C[(size_t)(row + 3) * V_ + col] = v[3] + bsv;
      }
    }
  }
}

extern "C" void kernel_launch(void* const* d_in, const int* in_sizes, int n_in,
                              void* d_out, int out_size, void* d_ws, size_t ws_size,
                              hipStream_t stream) {
  (void)in_sizes; (void)n_in; (void)out_size; (void)ws_size;
  const int* tgt = (const int*)d_in[0];
  const float* dh = (const float*)d_in[1];
  const float* enc = (const float*)d_in[2];
  const unsigned char* mask = (const unsigned char*)d_in[3];
  const float* embW = (const float*)d_in[4];
  const float* Wih = (const float*)d_in[5];
  const float* Whh = (const float*)d_in[6];
  const float* bih = (const float*)d_in[7];
  const float* bhh = (const float*)d_in[8];
  const float* Wa = (const float*)d_in[9];
  const float* ba = (const float*)d_in[10];
  const float* Wc = (const float*)d_in[11];
  const float* bc = (const float*)d_in[12];
  const float* Ws = (const float*)d_in[13];
  const float* bs = (const float*)d_in[14];
  float* out = (float*)d_out;

  // workspace layout (~74.2 MB) — slotted write-once buffers
  char* w = (char*)d_ws;
  int* bar = (int*)w;                                   // 40960 B: flag b @ b*32
  float* x0buf = (float*)(w + 40960);                   // 32 slots * 16384 f (2 MB)
  float* x1buf = x0buf + 524288;                        // 32 slots * 16384 f (2 MB)
  float* attnbuf = x1buf + 524288;                      // 32 slots * 4096 f (0.5 MB)
  float* ctxbuf = attnbuf + 131072;                     // 32 slots * 16384 f (2 MB)
  float* gx0v = ctxbuf + 524288;                        // 1024*1536 f (6 MB)
  float* encp = gx0v + 1572864;                         // 4096*512 f (8 MB)
  unsigned short* cbf = (unsigned short*)(encp + 2097152);  // 1024*512 bf16 (1 MB)
  unsigned short* wsb = cbf + 524288;                   // VPAD*512 bf16 (51.5 MB)

  hipMemsetAsync(bar, 0, 40960, stream);
  cvt_kernel<<<25152, 256, 0, stream>>>(Ws, wsb);
  gemm_f32<0><<<dim3(24, 16), 256, 0, stream>>>(embW, Wih, bih, gx0v, tgt, 1536);
  gemm_f32<1><<<dim3(8, 64), 256, 0, stream>>>(enc, Wa, ba, encp, nullptr, 512);
  seq_kernel<<<256, 256, 0, stream>>>(dh, enc, mask, Whh, Wih, bih, bhh, Wc, bc,
                                      gx0v, encp, bar, x0buf, x1buf, attnbuf, ctxbuf,
                                      cbf, out + (size_t)1024 * V_);
  proj_kernel<<<dim3(8, 393), 256, 0, stream>>>(cbf, wsb, bs, out);
}

// Round 3
// 1898.254 us; speedup vs baseline: 1.2637x; 1.0182x over previous
//
#include <hip/hip_runtime.h>
#include <hip/hip_bf16.h>
#include <stdint.h>
#include <stddef.h>

// Problem constants
#define B_ 32
#define T_ 32
#define S_ 128
#define H_ 512
#define V_ 50257
#define VPAD 50304
#define TH3 1536   // 3*H

typedef __attribute__((ext_vector_type(8))) short short8x;
typedef __attribute__((ext_vector_type(4))) float f32x4;

__device__ __forceinline__ float sigf(float x) { return 1.f / (1.f + __expf(-x)); }
__device__ __forceinline__ float tanhfast(float x) {
  float e = __expf(2.f * x);
  return 1.f - 2.f / (e + 1.f);
}
__device__ __forceinline__ unsigned short f2bf(float x) {
  unsigned int u = __float_as_uint(x);
  return (unsigned short)((u + 0x7fffu + ((u >> 16) & 1u)) >> 16);
}
__device__ __forceinline__ float dot4(float4 a, float4 b) {
  return a.x * b.x + a.y * b.y + a.z * b.z + a.w * b.w;
}

__device__ __forceinline__ void async16(const unsigned short* g, short* l) {
  __builtin_amdgcn_global_load_lds(
      (const __attribute__((address_space(1))) unsigned int*)g,
      (__attribute__((address_space(3))) unsigned int*)l, 16, 0, 0);
}

// Write-through (L1+L2 bypass) stores: data reaches the coherent point so
// other XCDs' cached first-touch reads of write-once slots see it.
__device__ __forceinline__ void store_wt(float* p, float v) {
  asm volatile("global_store_dword %0, %1, off sc0 sc1" :: "v"(p), "v"(v) : "memory");
}
__device__ __forceinline__ void store_wt4(float* p, f32x4 v) {
  asm volatile("global_store_dwordx4 %0, %1, off sc0 sc1" :: "v"(p), "v"(v) : "memory");
}

// ---------------- dataflow sync primitives ----------------
// Flags: one int per (step, producer-block), 128B-strided, write-once (0 -> 1),
// memset at launch, never reused => monotonic, no reset races.
// wait_flags: lanes of wave 0 sweep up to 128 flags with uncached loads
// (1-2 wave-instructions per sweep), __all ballot, s_sleep backoff. Lanes that
// found their flag stop loading, so poll traffic decays while waiting.
__device__ __forceinline__ void wait_flags(const int* flags, int n) {
  if (threadIdx.x < 64) {
    const int j = threadIdx.x;
    bool d0 = (j >= n), d1 = (j + 64 >= n);
    while (true) {
      if (!d0) d0 = __hip_atomic_load(flags + (size_t)j * 32, __ATOMIC_RELAXED,
                                      __HIP_MEMORY_SCOPE_SYSTEM) != 0;
      if (!d1) d1 = __hip_atomic_load(flags + (size_t)(j + 64) * 32, __ATOMIC_RELAXED,
                                      __HIP_MEMORY_SCOPE_SYSTEM) != 0;
      if (__all(d0 && d1)) break;
      __builtin_amdgcn_s_sleep(4);
    }
  }
  __syncthreads();
}

// Drain this block's write-through stores (inline-asm stores are invisible to
// the compiler's waitcnt bookkeeping => explicit per-wave vmcnt(0)), then
// publish the block's arrival flag with an uncached store.
__device__ __forceinline__ void drain_and_flag(int* flag) {
  asm volatile("s_waitcnt vmcnt(0)" ::: "memory");
  __syncthreads();
  if (threadIdx.x == 0)
    __hip_atomic_store(flag, 1, __ATOMIC_RELAXED, __HIP_MEMORY_SCOPE_SYSTEM);
}

// ---------------- Ws fp32 -> bf16 (padded to VPAD, pad rows zero) ----------------
__global__ __launch_bounds__(256) void cvt_kernel(const float* __restrict__ Ws,
                                                  unsigned short* __restrict__ outb) {
  size_t i = ((size_t)blockIdx.x * 256 + threadIdx.x) * 4;
  if (i >= (size_t)VPAD * 512) return;
  float4 f;
  if (i < (size_t)V_ * 512) f = *(const float4*)(Ws + i);
  else f = make_float4(0.f, 0.f, 0.f, 0.f);
  ushort4 u;
  u.x = f2bf(f.x); u.y = f2bf(f.y); u.z = f2bf(f.z); u.w = f2bf(f.w);
  *(ushort4*)(outb + i) = u;
}

// ---------------- generic fp32 tiled GEMM: C[M,N] = A[M,512] * Bw[N,512]^T + bias ----
template <int MODE>
__global__ __launch_bounds__(256) void gemm_f32(const float* __restrict__ Asrc,
                                                const float* __restrict__ Bw,
                                                const float* __restrict__ bias,
                                                float* __restrict__ Cout,
                                                const int* __restrict__ tgt, int N) {
  __shared__ __align__(16) float As[16][68];
  __shared__ __align__(16) float Bs[16][68];
  const int tid = threadIdx.x;
  const int tx = tid & 15, ty = tid >> 4;
  const int m0 = blockIdx.y * 64, n0 = blockIdx.x * 64;
  const int srow = tid >> 2, skq = (tid & 3) * 4;
  const float* arow;
  {
    int m = m0 + srow;
    if (MODE == 0) {
      int t = m >> 5, b = m & 31;
      int tok = (t == 0) ? 1 : tgt[b * 32 + t - 1];
      arow = Asrc + (size_t)tok * 512;
    } else {
      int b = m >> 7, s = m & 127;
      arow = Asrc + ((size_t)s * 32 + b) * 512;
    }
  }
  const float* brow = Bw + (size_t)(n0 + srow) * 512;
  float acc[4][4] = {};
  for (int k0 = 0; k0 < 512; k0 += 16) {
    float4 av = *(const float4*)(arow + k0 + skq);
    float4 bv = *(const float4*)(brow + k0 + skq);
    __syncthreads();
    As[skq + 0][srow] = av.x; As[skq + 1][srow] = av.y;
    As[skq + 2][srow] = av.z; As[skq + 3][srow] = av.w;
    Bs[skq + 0][srow] = bv.x; Bs[skq + 1][srow] = bv.y;
    Bs[skq + 2][srow] = bv.z; Bs[skq + 3][srow] = bv.w;
    __syncthreads();
#pragma unroll
    for (int kk = 0; kk < 16; ++kk) {
      float4 a4 = *(const float4*)&As[kk][ty * 4];
      float4 b4 = *(const float4*)&Bs[kk][tx * 4];
      acc[0][0] += a4.x * b4.x; acc[0][1] += a4.x * b4.y; acc[0][2] += a4.x * b4.z; acc[0][3] += a4.x * b4.w;
      acc[1][0] += a4.y * b4.x; acc[1][1] += a4.y * b4.y; acc[1][2] += a4.y * b4.z; acc[1][3] += a4.y * b4.w;
      acc[2][0] += a4.z * b4.x; acc[2][1] += a4.z * b4.y; acc[2][2] += a4.z * b4.z; acc[2][3] += a4.z * b4.w;
      acc[3][0] += a4.w * b4.x; acc[3][1] += a4.w * b4.y; acc[3][2] += a4.w * b4.z; acc[3][3] += a4.w * b4.w;
    }
  }
  float4 b4 = *(const float4*)(bias + n0 + tx * 4);
#pragma unroll
  for (int i = 0; i < 4; ++i) {
    float4 o;
    o.x = acc[i][0] + b4.x; o.y = acc[i][1] + b4.y;
    o.z = acc[i][2] + b4.z; o.w = acc[i][3] + b4.w;
    *(float4*)(Cout + (size_t)(m0 + ty * 4 + i) * N + n0 + tx * 4) = o;
  }
}

// CAT: one output row gg over batches b2 (per 32-lane group), weights from LDS.
__device__ __forceinline__ void cat_rows(int t, int gg, int b2, const float* wr,
                                         const float* __restrict__ ctxbuf,
                                         const float* __restrict__ x1buf,
                                         const float* __restrict__ bc,
                                         unsigned short* __restrict__ cbf) {
  const float* ctx = ctxbuf + (size_t)t * 16384 + b2 * 512;
  const float* x1c = x1buf + (size_t)t * 16384 + b2 * 512;
  float a = bc[gg];
#pragma unroll 4
  for (int k = 0; k < 512; k += 4) a += dot4(*(const float4*)(wr + k), *(const float4*)(ctx + k));
#pragma unroll 4
  for (int k = 0; k < 512; k += 4) a += dot4(*(const float4*)(wr + 512 + k), *(const float4*)(x1c + k));
  cbf[((size_t)t * 32 + b2) * 512 + gg] = f2bf(tanhfast(a));
}

// ---------------- persistent DATAFLOW sequential kernel ----------------
// 256 blocks x 256 threads. NO grid barrier: per-dependency flag groups.
// roles: [0,64)   L0 : x0(t) <- x0(t-1)            waits fx0(t-1)[64]
//        [64,192) L1 : x1(t) <- x0(t), x1(t-1)     waits fx0(t)[64], fx1(t-1)[128]
//        [192,224)ATT-S: softmax(t) <- x1(t)       waits fx1(t)[128]; then CAT(t-1)
//        [224,256)ATT-C: ctx(t) <- attn(t)         waits fattn(t)[1];  then CAT(t-1)
// Weights preloaded once into LDS. Cross-block buffers are WRITE-ONCE SLOTTED;
// producers store write-through (sc0 sc1), consumers use cached first-touch
// loads. Producers drain (vmcnt 0) then publish an uncached flag; consumers
// sweep producer flags with one 64-lane uncached wave-load + __all.
__global__ __launch_bounds__(256) void seq_kernel(
    const float* __restrict__ dh, const float* __restrict__ enc,
    const unsigned char* __restrict__ mask,
    const float* __restrict__ Whh, const float* __restrict__ Wih,
    const float* __restrict__ bih, const float* __restrict__ bhh,
    const float* __restrict__ Wc, const float* __restrict__ bc,
    const float* __restrict__ gx0v, const float* __restrict__ encp,
    int* __restrict__ bar, float* __restrict__ x0buf, float* __restrict__ x1buf,
    float* __restrict__ attnbuf, float* __restrict__ ctxbuf,
    unsigned short* __restrict__ cbf, float* __restrict__ out_hf) {
  const int tid = threadIdx.x, bid = blockIdx.x;
  __shared__ __align__(16) float sm[3456];
  __shared__ __align__(16) float wlds[12288];  // 48 KB weight cache
  const int lane = tid & 63, wv = tid >> 6;
  const int bb = lane & 31, rh = lane >> 5;  // lane = (batch, row-half)

  int* fx0 = bar;                 // 32 steps * 64 flags * 32-int stride
  int* fx1 = bar + 65536;         // 32 * 128 * 32
  int* fattn = bar + 196608;      // 32 * 32 * 32
  int* fctx = bar + 229376;       // 32 * 32 * 32   (total 1 MB)

  // ---------------- one-time weight preload into LDS ----------------
  if (bid < 64) {
    const int iset0 = bid * 8;
    for (int idx = tid; idx < 24 * 128; idx += 256) {
      const int rloc = idx >> 7, kq = (idx & 127) << 2;
      const int g = rloc >> 3, ii = rloc & 7;
      *(float4*)&wlds[rloc * 512 + kq] =
          *(const float4*)(Whh + (size_t)(g * 512 + iset0 + ii) * 512 + kq);
    }
  } else if (bid < 192) {
    const int iset0 = (bid - 64) * 4;
    for (int idx = tid; idx < 12 * 128; idx += 256) {
      const int rloc = idx >> 7, kq = (idx & 127) << 2;
      const int g = rloc >> 2, ii = rloc & 3;
      const size_t off = (size_t)(1536 + g * 512 + iset0 + ii) * 512 + kq;
      *(float4*)&wlds[rloc * 512 + kq] = *(const float4*)(Wih + off);
      *(float4*)&wlds[(12 + rloc) * 512 + kq] = *(const float4*)(Whh + off);
    }
  } else {
    const int gg0 = (bid < 224) ? (bid - 192) * 8 : 256 + (bid - 224) * 8;
    for (int idx = tid; idx < 8 * 256; idx += 256) {
      const int r = idx >> 8, kq = (idx & 255) << 2;
      *(float4*)&wlds[r * 1024 + kq] =
          *(const float4*)(Wc + (size_t)(gg0 + r) * 1024 + kq);
    }
  }
  __syncthreads();

  if (bid < 64) {
    // ---------------- L0 : independent recurrence, sprints ahead ----------------
    const int iset0 = bid * 8;
    for (int t = 0; t < 32; ++t) {
      if (t > 0) wait_flags(fx0 + (size_t)(t - 1) * 2048, 64);
      const float* xsrc = (t == 0) ? dh : (x0buf + (size_t)(t - 1) * 16384);
      float acc[12];
#pragma unroll
      for (int r = 0; r < 12; ++r) acc[r] = 0.f;
      const float* xb = xsrc + bb * 512 + wv * 128;
      for (int c = 0; c < 4; ++c) {
        float4 xv[8];
#pragma unroll
        for (int u = 0; u < 8; ++u) xv[u] = *(const float4*)(xb + c * 32 + u * 4);
#pragma unroll
        for (int rr = 0; rr < 12; ++rr) {
          const int rloc = rh * 12 + rr;
          const float* wrow = wlds + (size_t)rloc * 512 + wv * 128 + c * 32;
#pragma unroll
          for (int u = 0; u < 8; ++u)
            acc[rr] += dot4(*(const float4*)(wrow + u * 4), xv[u]);
        }
      }
      __syncthreads();
#pragma unroll
      for (int rr = 0; rr < 12; ++rr)
        sm[wv * 768 + (rh * 12 + rr) * 32 + bb] = acc[rr];
      __syncthreads();
      {
        const int b2 = tid & 31, i2 = tid >> 5;  // i2 in [0,8)
        const int ig = iset0 + i2;
        float s0 = bhh[ig], s1 = bhh[512 + ig], s2 = bhh[1024 + ig];
#pragma unroll
        for (int w = 0; w < 4; ++w) {
          s0 += sm[w * 768 + (i2) * 32 + b2];
          s1 += sm[w * 768 + (8 + i2) * 32 + b2];
          s2 += sm[w * 768 + (16 + i2) * 32 + b2];
        }
        const float* gx = gx0v + ((size_t)t * 32 + b2) * 1536;
        const float hv = xsrc[b2 * 512 + ig];
        const float r = sigf(gx[ig] + s0);
        const float z = sigf(gx[512 + ig] + s1);
        const float n = tanhfast(gx[1024 + ig] + r * s2);
        const float xn = (1.f - z) * n + z * hv;
        store_wt(x0buf + (size_t)t * 16384 + b2 * 512 + ig, xn);
        if (t == 31) out_hf[b2 * 512 + ig] = xn;
      }
      drain_and_flag(fx0 + ((size_t)t * 64 + bid) * 32);
    }
  } else if (bid < 192) {
    // ---------------- L1 : the critical recurrence ----------------
    const int iset0 = (bid - 64) * 4;
    for (int t = 0; t < 32; ++t) {
      wait_flags(fx0 + (size_t)t * 2048, 64);
      if (t > 0) wait_flags(fx1 + (size_t)(t - 1) * 4096, 128);
      const float* xs0 = x0buf + (size_t)t * 16384;
      const float* xs1 = (t == 0) ? (dh + 16384) : (x1buf + (size_t)(t - 1) * 16384);
      float acc[12];
#pragma unroll
      for (int r = 0; r < 12; ++r) acc[r] = 0.f;
      // pass 1: gx1 = Wih1 . x0(t)
      {
        const float* xb = xs0 + bb * 512 + wv * 128;
        for (int c = 0; c < 4; ++c) {
          float4 xv[8];
#pragma unroll
          for (int u = 0; u < 8; ++u) xv[u] = *(const float4*)(xb + c * 32 + u * 4);
#pragma unroll
          for (int rr = 0; rr < 6; ++rr) {
            const int rloc = rh * 6 + rr;
            const float* wrow = wlds + (size_t)rloc * 512 + wv * 128 + c * 32;
#pragma unroll
            for (int u = 0; u < 8; ++u)
              acc[rr] += dot4(*(const float4*)(wrow + u * 4), xv[u]);
          }
        }
      }
      // pass 2: gh1 = Whh1 . x1(t-1)
      {
        const float* xb = xs1 + bb * 512 + wv * 128;
        for (int c = 0; c < 4; ++c) {
          float4 xv[8];
#pragma unroll
          for (int u = 0; u < 8; ++u) xv[u] = *(const float4*)(xb + c * 32 + u * 4);
#pragma unroll
          for (int rr = 0; rr < 6; ++rr) {
            const int rloc = rh * 6 + rr;
            const float* wrow = wlds + (size_t)(12 + rloc) * 512 + wv * 128 + c * 32;
#pragma unroll
            for (int u = 0; u < 8; ++u)
              acc[6 + rr] += dot4(*(const float4*)(wrow + u * 4), xv[u]);
          }
        }
      }
      __syncthreads();
#pragma unroll
      for (int rr = 0; rr < 6; ++rr) {
        sm[wv * 768 + (rh * 6 + rr) * 32 + bb] = acc[rr];
        sm[wv * 768 + (12 + rh * 6 + rr) * 32 + bb] = acc[6 + rr];
      }
      __syncthreads();
      if (tid < 128) {
        const int b2 = tid & 31, i2 = tid >> 5;  // i2 in [0,4)
        const int ig = iset0 + i2;
        float gxs[3], ghs[3];
#pragma unroll
        for (int g = 0; g < 3; ++g) {
          float a = bih[1536 + g * 512 + ig];
          float h = bhh[1536 + g * 512 + ig];
#pragma unroll
          for (int w = 0; w < 4; ++w) {
            a += sm[w * 768 + (g * 4 + i2) * 32 + b2];
            h += sm[w * 768 + (12 + g * 4 + i2) * 32 + b2];
          }
          gxs[g] = a; ghs[g] = h;
        }
        const float hv = xs1[b2 * 512 + ig];
        const float r = sigf(gxs[0] + ghs[0]);
        const float z = sigf(gxs[1] + ghs[1]);
        const float n = tanhfast(gxs[2] + r * ghs[2]);
        const float xn = (1.f - z) * n + z * hv;
        store_wt(x1buf + (size_t)t * 16384 + b2 * 512 + ig, xn);
        if (t == 31) out_hf[16384 + b2 * 512 + ig] = xn;
      }
      drain_and_flag(fx1 + ((size_t)t * 128 + (bid - 64)) * 32);
    }
  } else if (bid < 224) {
    // ---------------- ATT-S : scores+softmax(t), then CAT(t-1) rows 0..255 ----
    const int b = bid - 192;
    const float* wr = wlds + (size_t)(tid >> 5) * 1024;
    const int gg = b * 8 + (tid >> 5), b2 = tid & 31;
    for (int t = 0; t < 32; ++t) {
      wait_flags(fx1 + (size_t)t * 4096, 128);
      {
        const float* x1 = x1buf + (size_t)t * 16384 + b * 512;
        const int s = tid >> 1, kh = tid & 1;
        const float* ep = encp + ((size_t)b * 128 + s) * 512 + kh * 256;
        const float* xx = x1 + kh * 256;
        float a = 0.f;
#pragma unroll 8
        for (int k = 0; k < 256; k += 4)
          a += dot4(*(const float4*)(ep + k), *(const float4*)(xx + k));
        sm[tid] = a;
        __syncthreads();
        if (tid < 128) {
          float sc = sm[2 * tid] + sm[2 * tid + 1];
          if (mask[b * 128 + tid]) sc = -1e9f;
          sm[256 + tid] = sc;
        }
        __syncthreads();
        if (tid < 64) {
          float m1 = fmaxf(sm[256 + tid], sm[256 + tid + 64]);
#pragma unroll
          for (int off = 32; off; off >>= 1) m1 = fmaxf(m1, __shfl_xor(m1, off));
          float e0 = __expf(sm[256 + tid] - m1), e1 = __expf(sm[256 + tid + 64] - m1);
          float ssum = e0 + e1;
#pragma unroll
          for (int off = 32; off; off >>= 1) ssum += __shfl_xor(ssum, off);
          float inv = 1.f / ssum;
          sm[384 + tid] = e0 * inv;
          sm[384 + tid + 64] = e1 * inv;
        }
        __syncthreads();
        if (tid < 128) store_wt(attnbuf + (size_t)t * 4096 + b * 128 + tid, sm[384 + tid]);
      }
      drain_and_flag(fattn + ((size_t)t * 32 + b) * 32);
      if (t > 0) {
        wait_flags(fctx + (size_t)(t - 1) * 1024, 32);
        cat_rows(t - 1, gg, b2, wr, ctxbuf, x1buf, bc, cbf);
      }
    }
    wait_flags(fctx + (size_t)31 * 1024, 32);
    cat_rows(31, gg, b2, wr, ctxbuf, x1buf, bc, cbf);
  } else {
    // ---------------- ATT-C : ctx(t), then CAT(t-1) rows 256..511 ----------------
    const int b = bid - 224;
    const float* wr = wlds + (size_t)(tid >> 5) * 1024;
    const int gg = 256 + b * 8 + (tid >> 5), b2 = tid & 31;
    for (int t = 0; t < 32; ++t) {
      wait_flags(fattn + ((size_t)t * 32 + b) * 32, 1);
      if (tid < 128) sm[tid] = attnbuf[(size_t)t * 4096 + b * 128 + tid];
      __syncthreads();
      if (tid < 128) {
        const int h4 = tid * 4;
        float4 c = make_float4(0.f, 0.f, 0.f, 0.f);
#pragma unroll 8
        for (int s = 0; s < 128; ++s) {
          const float a = sm[s];
          const float4 e = *(const float4*)(enc + ((size_t)s * 32 + b) * 512 + h4);
          c.x += a * e.x; c.y += a * e.y; c.z += a * e.z; c.w += a * e.w;
        }
        f32x4 cc = {c.x, c.y, c.z, c.w};
        store_wt4(ctxbuf + (size_t)t * 16384 + b * 512 + h4, cc);
      }
      drain_and_flag(fctx + ((size_t)t * 32 + b) * 32);
      if (t > 0) {
        wait_flags(fx1 + (size_t)(t - 1) * 4096, 128);
        wait_flags(fctx + (size_t)(t - 1) * 1024, 32);
        cat_rows(t - 1, gg, b2, wr, ctxbuf, x1buf, bc, cbf);
      }
    }
    wait_flags(fx1 + (size_t)31 * 4096, 128);
    wait_flags(fctx + (size_t)31 * 1024, 32);
    cat_rows(31, gg, b2, wr, ctxbuf, x1buf, bc, cbf);
  }
}

// ---------------- bf16 MFMA vocab projection: C[1024,V] = concat * Ws^T + bs ---------
__global__ __launch_bounds__(256) void proj_kernel(const unsigned short* __restrict__ A,
                                                   const unsigned short* __restrict__ Bw,
                                                   const float* __restrict__ bs,
                                                   float* __restrict__ C) {
  __shared__ short8x AsV[512];
  __shared__ short8x BsV[512];
  short* As = (short*)AsV;
  short* Bs = (short*)BsV;
  const int tid = threadIdx.x;
  const int lane = tid & 63, wv = tid >> 6;
  const int m0 = blockIdx.x * 128;
  const int n0 = blockIdx.y * 128;
  const int wm = (wv >> 1) * 64, wn = (wv & 1) * 64;
  f32x4 acc[4][4] = {};
  const int sr = lane >> 2, sb = (lane & 3) * 8;
  const unsigned short* gA1 = A + (size_t)(m0 + wv * 16 + sr) * 512 + sb;
  const unsigned short* gA2 = gA1 + (size_t)64 * 512;
  const unsigned short* gB1 = Bw + (size_t)(n0 + wv * 16 + sr) * 512 + sb;
  const unsigned short* gB2 = gB1 + (size_t)64 * 512;
  short* lA1 = As + (wv * 16) * 32;
  short* lA2 = As + (64 + wv * 16) * 32;
  short* lB1 = Bs + (wv * 16) * 32;
  short* lB2 = Bs + (64 + wv * 16) * 32;
  const int rA = wm + (lane & 15);
  const int rB = wn + (lane & 15);
  const int kb = (lane >> 4) * 8;
  for (int kt = 0; kt < 16; ++kt) {
    const int ko = kt * 32;
    __syncthreads();
    async16(gA1 + ko, lA1);
    async16(gA2 + ko, lA2);
    async16(gB1 + ko, lB1);
    async16(gB2 + ko, lB2);
    __syncthreads();
    short8x af[4], bf[4];
#pragma unroll
    for (int i = 0; i < 4; ++i) af[i] = *(const short8x*)(As + (rA + i * 16) * 32 + kb);
#pragma unroll
    for (int i = 0; i < 4; ++i) bf[i] = *(const short8x*)(Bs + (rB + i * 16) * 32 + kb);
#pragma unroll
    for (int mo = 0; mo < 4; ++mo)
#pragma unroll
      for (int no = 0; no < 4; ++no)
        acc[mo][no] = __builtin_amdgcn_mfma_f32_16x16x32_bf16(af[mo], bf[no], acc[mo][no], 0, 0, 0);
  }
#pragma unroll
  for (int no = 0; no < 4; ++no) {
    const int col = n0 + wn + no * 16 + (lane & 15);
    if (col < V_) {
      const float bsv = bs[col];
#pragma unroll
      for (int mo = 0; mo < 4; ++mo) {
        const int row = m0 + wm + mo * 16 + ((lane >> 4) << 2);
        f32x4 v = acc[mo][no];
        C[(size_t)(row + 0) * V_ + col] = v[0] + bsv;
        C[(size_t)(row + 1) * V_ + col] = v[1] + bsv;
        C[(size_t)(row + 2) * V_ + col] = v[2] + bsv;
        C[(size_t)(row + 3) * V_ + col] = v[3] + bsv;
      }
    }
  }
}

extern "C" void kernel_launch(void* const* d_in, const int* in_sizes, int n_in,
                              void* d_out, int out_size, void* d_ws, size_t ws_size,
                              hipStream_t stream) {
  (void)in_sizes; (void)n_in; (void)out_size; (void)ws_size;
  const int* tgt = (const int*)d_in[0];
  const float* dh = (const float*)d_in[1];
  const float* enc = (const float*)d_in[2];
  const unsigned char* mask = (const unsigned char*)d_in[3];
  const float* embW = (const float*)d_in[4];
  const float* Wih = (const float*)d_in[5];
  const float* Whh = (const float*)d_in[6];
  const float* bih = (const float*)d_in[7];
  const float* bhh = (const float*)d_in[8];
  const float* Wa = (const float*)d_in[9];
  const float* ba = (const float*)d_in[10];
  const float* Wc = (const float*)d_in[11];
  const float* bc = (const float*)d_in[12];
  const float* Ws = (const float*)d_in[13];
  const float* bs = (const float*)d_in[14];
  float* out = (float*)d_out;

  // workspace layout (~75 MB) — 1 MB flag region + slotted write-once buffers
  char* w = (char*)d_ws;
  int* bar = (int*)w;                                   // 1 MB flags
  float* x0buf = (float*)(w + (1 << 20));               // 32 slots * 16384 f (2 MB)
  float* x1buf = x0buf + 524288;                        // 32 slots * 16384 f (2 MB)
  float* attnbuf = x1buf + 524288;                      // 32 slots * 4096 f (0.5 MB)
  float* ctxbuf = attnbuf + 131072;                     // 32 slots * 16384 f (2 MB)
  float* gx0v = ctxbuf + 524288;                        // 1024*1536 f (6 MB)
  float* encp = gx0v + 1572864;                         // 4096*512 f (8 MB)
  unsigned short* cbf = (unsigned short*)(encp + 2097152);  // 1024*512 bf16 (1 MB)
  unsigned short* wsb = cbf + 524288;                   // VPAD*512 bf16 (51.5 MB)

  hipMemsetAsync(bar, 0, 1 << 20, stream);
  cvt_kernel<<<25152, 256, 0, stream>>>(Ws, wsb);
  gemm_f32<0><<<dim3(24, 16), 256, 0, stream>>>(embW, Wih, bih, gx0v, tgt, 1536);
  gemm_f32<1><<<dim3(8, 64), 256, 0, stream>>>(enc, Wa, ba, encp, nullptr, 512);
  seq_kernel<<<256, 256, 0, stream>>>(dh, enc, mask, Whh, Wih, bih, bhh, Wc, bc,
                                      gx0v, encp, bar, x0buf, x1buf, attnbuf, ctxbuf,
                                      cbf, out + (size_t)1024 * V_);
  proj_kernel<<<dim3(8, 393), 256, 0, stream>>>(cbf, wsb, bs, out);
}